// Round 25
// baseline (204.948 us; speedup 1.0000x reference)
//
#include <hip/hip_runtime.h>
#include <stdint.h>

#define NHEAD 16
#define SEQ 2048
#define BATCH 4
#define NT (SEQ / 64)   // 32 kv tiles of 64

typedef short short8 __attribute__((ext_vector_type(8)));     // 8 bf16 (4 VGPRs)
typedef _Float16 half8 __attribute__((ext_vector_type(8)));   // 8 fp16 (4 VGPRs)
typedef _Float16 half4 __attribute__((ext_vector_type(4)));   // 4 fp16 (8B)
typedef float f32x4  __attribute__((ext_vector_type(4)));     // MFMA accumulator
typedef __bf16 bf16x2 __attribute__((ext_vector_type(2)));

typedef const __attribute__((address_space(1))) void* gas_t;
typedef __attribute__((address_space(3))) void* las_t;
#define GLL16(g, s) __builtin_amdgcn_global_load_lds((gas_t)(g), (las_t)(s), 16, 0, 0)

static __device__ __forceinline__ unsigned short f2bfn(float f) {
    union { __bf16 b; unsigned short u; } cv;
    cv.b = (__bf16)f;
    return cv.u;
}
static __device__ __forceinline__ uint32_t pkbf(float a, float b) {
    union { bf16x2 v; uint32_t u; } cv;
    cv.v[0] = (__bf16)a; cv.v[1] = (__bf16)b;
    return cv.u;
}
static __device__ __forceinline__ float exp2_fast(float x) {
#if __has_builtin(__builtin_amdgcn_exp2f)
    return __builtin_amdgcn_exp2f(x);
#else
    float r; asm("v_exp_f32 %0, %1\n\ts_nop 0" : "=v"(r) : "v"(x)); return r;
#endif
}

// ---------------------------------------------------------------------------
// Merged fp32 -> fp16 conversion for x, w_qkv, w_proj (one launch).
// ---------------------------------------------------------------------------
__global__ __launch_bounds__(256)
void conv3(const float* __restrict__ x,  _Float16* __restrict__ Xf,
           const float* __restrict__ wq, _Float16* __restrict__ Wf,
           const float* __restrict__ wp, _Float16* __restrict__ Wpf) {
    const int bid = blockIdx.x;
    const float* src;
    _Float16* dst;
    int base;
    if (bid < 4096)      { src = x;  dst = Xf;  base = bid; }
    else if (bid < 5632) { src = wq; dst = Wf;  base = bid - 4096; }
    else                 { src = wp; dst = Wpf; base = bid - 5632; }
    const int idx = (base * 256 + threadIdx.x) * 8;
    float4 v0 = *(const float4*)(src + idx);
    float4 v1 = *(const float4*)(src + idx + 4);
    half8 h;
    h[0] = (_Float16)v0.x; h[1] = (_Float16)v0.y;
    h[2] = (_Float16)v0.z; h[3] = (_Float16)v0.w;
    h[4] = (_Float16)v1.x; h[5] = (_Float16)v1.y;
    h[6] = (_Float16)v1.z; h[7] = (_Float16)v1.w;
    *(half8*)(dst + idx) = h;
}

// ---------------------------------------------------------------------------
// fp16 MFMA GEMM — B DIRECT-FROM-GLOBAL this round. 256x128 macro-tile,
// 4 waves (2Mx2N), wave owns 128x64 (8x4 frags). A staged via 3-buffer
// depth-2 GLL16 (LDS now A-only, 3x16KB); B fragments loaded straight
// global->VGPR (weights are L2-hot; per row the 4 g-lanes fetch 64
// contiguous bytes), double-buffered in registers with parity unroll.
// LDS reads per K-step 12 -> 8 (the LDS pipe was the GEMM bottleneck).
// Counted vmcnt(8): A(ks+1)'s 4 GLL16s drain behind A(ks+2)+B(ks+1).
// Compile-time SWP operand order + vectorized epilogues (unchanged).
// ---------------------------------------------------------------------------
template<int EPI, int SWP>
__global__ __launch_bounds__(256, 2)
void gemm_h(const _Float16* __restrict__ Af, const _Float16* __restrict__ Bf,
            int K, int N, int nbx, int bnoff,
            float* __restrict__ outF, const float* __restrict__ bias,
            unsigned short* __restrict__ Qb, unsigned short* __restrict__ Kb,
            unsigned short* __restrict__ Vt) {
    __shared__ _Float16 lds[3][8192];   // [buf][ A 256x32 ]

    const int tid = threadIdx.x;
    const int l = tid & 63, wv = tid >> 6;
    const int wm = wv >> 1, wn = wv & 1;       // 2 M-waves x 2 N-waves
    const int c = l & 15, g = l >> 4;

    const int id = blockIdx.x;
    const int xcd = id & 7, s = id >> 3;
    const int bpx = (gridDim.x >> 3) / nbx;    // by-rows per XCD
    const int by = xcd * bpx + s / nbx, bx = s % nbx;
    const int bm = by * 256, bn = bnoff + bx * 128;

    // A staging: 1024 16B-chunks (4/thread); source column pre-swizzled.
    size_t aoff[4];
    int ldsA[4];
    #pragma unroll
    for (int u = 0; u < 4; ++u) {
        const int i = u * 256 + tid;
        const int row = i >> 2;
        const int gg = (i & 3) ^ ((row >> 1) & 3);
        aoff[u] = (size_t)(bm + row) * K + gg * 8;
        ldsA[u] = (u * 256 + wv * 64) * 8;
    }

    // A frag read offsets (swizzle-matched), constant across K
    int offA[8];
    #pragma unroll
    for (int m = 0; m < 8; ++m) {
        const int row = wm * 128 + m * 16 + c;
        offA[m] = row * 32 + (g ^ ((row >> 1) & 3)) * 8;
    }
    // B frag global pointers (natural layout, no swizzle)
    const _Float16* bp[4];
    #pragma unroll
    for (int n = 0; n < 4; ++n) {
        const int row = bn + wn * 64 + n * 16 + c;
        bp[n] = Bf + (size_t)row * K + g * 8;
    }

    #define GSTAGE(buf, kk) do {                              \
        _Pragma("unroll")                                     \
        for (int u = 0; u < 4; ++u)                           \
            GLL16(Af + aoff[u] + (kk), &lds[buf][ldsA[u]]);   \
    } while (0)

    f32x4 acc[8][4] = {};
    half8 bfrA[4], bfrB[4];
    const int NK = K >> 5;

    // prologue: A0, B0, A1; wait A0+B0 (A1 still in flight)
    GSTAGE(0, 0);
    #pragma unroll
    for (int n = 0; n < 4; ++n) bfrA[n] = *(const half8*)(bp[n]);
    GSTAGE(1, 32);
    asm volatile("s_waitcnt vmcnt(4)" ::: "memory");
    __builtin_amdgcn_s_barrier();
    __builtin_amdgcn_sched_barrier(0);

    #define BODYG(ksv, BC, BN)                                                 \
    {                                                                          \
        const int cur = (ksv) % 3;                                             \
        if ((ksv) + 2 < NK) GSTAGE(((ksv) + 2) % 3, ((ksv) + 2) * 32);         \
        if ((ksv) + 1 < NK) {                                                  \
            _Pragma("unroll")                                                  \
            for (int n = 0; n < 4; ++n)                                        \
                BN[n] = *(const half8*)(bp[n] + ((ksv) + 1) * 32);             \
        }                                                                      \
        half8 a[8];                                                            \
        _Pragma("unroll")                                                      \
        for (int m = 0; m < 8; ++m) a[m] = *(const half8*)&lds[cur][offA[m]];  \
        __builtin_amdgcn_s_setprio(1);                                         \
        _Pragma("unroll")                                                      \
        for (int m = 0; m < 8; ++m)                                            \
            _Pragma("unroll")                                                  \
            for (int n = 0; n < 4; ++n) {                                      \
                if constexpr (SWP)                                             \
                    acc[m][n] = __builtin_amdgcn_mfma_f32_16x16x32_f16(        \
                        BC[n], a[m], acc[m][n], 0, 0, 0);                      \
                else                                                           \
                    acc[m][n] = __builtin_amdgcn_mfma_f32_16x16x32_f16(        \
                        a[m], BC[n], acc[m][n], 0, 0, 0);                      \
            }                                                                  \
        __builtin_amdgcn_s_setprio(0);                                         \
        if ((ksv) + 1 < NK) {                                                  \
            if ((ksv) + 2 < NK) {                                              \
                asm volatile("s_waitcnt vmcnt(8)" ::: "memory");               \
            } else {                                                           \
                asm volatile("s_waitcnt vmcnt(0)" ::: "memory");               \
            }                                                                  \
            __builtin_amdgcn_s_barrier();                                      \
            __builtin_amdgcn_sched_barrier(0);                                 \
        }                                                                      \
    }

    for (int t = 0; t < NK; t += 2) {
        BODYG(t, bfrA, bfrB);
        BODYG(t + 1, bfrB, bfrA);
    }
    #undef BODYG
    #undef GSTAGE

    if constexpr (EPI == 0) {
        const int colbase = bn + wn * 64;                   // 64-aligned
        const int which = colbase >> 10;
        const int h = (colbase >> 6) & 15;
        if constexpr (SWP) {
            const float qs = 0.125f * 1.44269504088896340736f;
            unsigned short* plane = (which == 0) ? Qb : Kb;
            const float sc = (which == 0) ? qs : 1.0f;
            #pragma unroll
            for (int m = 0; m < 8; ++m) {
                const int t = bm + wm * 128 + m * 16 + c;
                const int bb = t >> 11, nl = t & 2047;
                unsigned short* rowp = plane +
                    ((size_t)(bb * NHEAD + h) * SEQ + nl) * 64;
                #pragma unroll
                for (int n = 0; n < 4; ++n) {
                    ushort4 o;
                    o.x = f2bfn(acc[m][n][0] * sc);
                    o.y = f2bfn(acc[m][n][1] * sc);
                    o.z = f2bfn(acc[m][n][2] * sc);
                    o.w = f2bfn(acc[m][n][3] * sc);
                    *(ushort4*)(rowp + n * 16 + 4 * g) = o;
                }
            }
        } else {
            #pragma unroll
            for (int m = 0; m < 8; ++m) {
                const int trow0 = bm + wm * 128 + m * 16 + 4 * g;
                const int bb = trow0 >> 11, nl0 = trow0 & 2047;
                #pragma unroll
                for (int n = 0; n < 4; ++n) {
                    const int d = n * 16 + c;
                    ushort4 o;
                    o.x = f2bfn(acc[m][n][0]);
                    o.y = f2bfn(acc[m][n][1]);
                    o.z = f2bfn(acc[m][n][2]);
                    o.w = f2bfn(acc[m][n][3]);
                    *(ushort4*)(Vt + ((size_t)(bb * NHEAD + h) * 64 + d) * SEQ + nl0) = o;
                }
            }
        }
    } else {
        #pragma unroll
        for (int m = 0; m < 8; ++m) {
            const int t = bm + wm * 128 + m * 16 + c;
            #pragma unroll
            for (int n = 0; n < 4; ++n) {
                const int col0 = bn + wn * 64 + n * 16 + 4 * g;
                float4 bv = *(const float4*)&bias[col0];
                float4 o;
                o.x = acc[m][n][0] + bv.x;
                o.y = acc[m][n][1] + bv.y;
                o.z = acc[m][n][2] + bv.z;
                o.w = acc[m][n][3] + bv.w;
                *(float4*)&outF[(size_t)t * N + col0] = o;
            }
        }
    }
}

// ---------------------------------------------------------------------------
// MFMA flash attention (r24, unchanged): two tiles per barrier span, 4 LDS
// buffer pairs, shared-zero C, MFMA-l, tau' in-register P, swapped PV.
// ---------------------------------------------------------------------------
__global__ __launch_bounds__(512)
void attn_mfma(const unsigned short* __restrict__ Qb, const unsigned short* __restrict__ Kb,
               const unsigned short* __restrict__ Vt, _Float16* __restrict__ Of) {
    __shared__ unsigned short Kl[4][4096];   // [buf][64 row][64 d], rows = tau'-permuted kv
    __shared__ unsigned short Vl[4][4096];   // [buf][64 d][64 kv], natural kv

    const int tid = threadIdx.x;
    const int l = tid & 63, w = tid >> 6;
    const int g = l >> 4, c = l & 15;
    const int sw = (c & 7) << 4;

    const int blk = blockIdx.x;
    const int xcd = blk & 7, s0 = blk >> 3;        // s0 = 0..31
    const int bh = xcd * 8 + (s0 >> 2);
    const int b = bh >> 4, h = bh & 15;
    const int q0 = (s0 & 3) * 512;

    const unsigned short* QbBH = Qb + (size_t)bh * SEQ * 64;
    const unsigned short* KbBH = Kb + (size_t)bh * SEQ * 64;
    const unsigned short* VtBH = Vt + (size_t)bh * 64 * SEQ;

    const int r0 = tid >> 3;
    const int tau0 = (r0 & 32) | ((r0 & 12) << 1) | ((r0 & 16) >> 2) | (r0 & 3);
    const unsigned short* sK0 = KbBH + (size_t)tau0 * 64 + ((tid & 7) ^ (r0 & 7)) * 8;
    const unsigned short* sV0 = VtBH + (size_t)r0 * SEQ + ((tid & 7) ^ (r0 & 7)) * 8;

    #define STAGE(nb, tt) do {                                        \
        GLL16(sK0 + (size_t)(tt) * 4096, (char*)Kl[nb] + tid * 16);   \
        GLL16(sV0 + (tt) * 64,           (char*)Vl[nb] + tid * 16);   \
    } while (0)

    int rdoff[2][4];
    #pragma unroll
    for (int s = 0; s < 2; ++s)
        #pragma unroll
        for (int f = 0; f < 4; ++f)
            rdoff[s][f] = (f * 16 + c) * 128 + ((g * 16 + s * 64) ^ sw);

    short8 qf[4][2];
    #pragma unroll
    for (int m = 0; m < 4; ++m)
        #pragma unroll
        for (int s = 0; s < 2; ++s)
            qf[m][s] = *(const short8*)(QbBH +
                         (size_t)(q0 + w * 64 + m * 16 + c) * 64 + s * 32 + g * 8);

    const short8 ones = {0x3F80, 0x3F80, 0x3F80, 0x3F80,
                         0x3F80, 0x3F80, 0x3F80, 0x3F80};   // bf16 1.0
    const f32x4 z4 = {0.f, 0.f, 0.f, 0.f};                  // shared zero C-in

    f32x4 oacc[4][4] = {};
    f32x4 lacc[4] = {};

    STAGE(0, 0);
    STAGE(1, 1);

    #define QK(bb, st)                                                         \
    {                                                                          \
        short8 kf[4];                                                          \
        _Pragma("unroll")                                                      \
        for (int f = 0; f < 4; ++f)                                            \
            kf[f] = *(const short8*)((char*)Kl[bb] + rdoff[0][f]);             \
        __builtin_amdgcn_s_setprio(1);                                         \
        _Pragma("unroll")                                                      \
        for (int m = 0; m < 4; ++m)                                            \
            _Pragma("unroll")                                                  \
            for (int f = 0; f < 4; ++f)                                        \
                st[m][f] = __builtin_amdgcn_mfma_f32_16x16x32_bf16(            \
                    kf[f], qf[m][0], z4, 0, 0, 0);                             \
        __builtin_amdgcn_s_setprio(0);                                         \
        _Pragma("unroll")                                                      \
        for (int f = 0; f < 4; ++f)                                            \
            kf[f] = *(const short8*)((char*)Kl[bb] + rdoff[1][f]);             \
        __builtin_amdgcn_s_setprio(1);                                         \
        _Pragma("unroll")                                                      \
        for (int m = 0; m < 4; ++m)                                            \
            _Pragma("unroll")                                                  \
            for (int f = 0; f < 4; ++f)                                        \
                st[m][f] = __builtin_amdgcn_mfma_f32_16x16x32_bf16(            \
                    kf[f], qf[m][1], st[m][f], 0, 0, 0);                       \
        __builtin_amdgcn_s_setprio(0);                                         \
    }

    #define SM(st, pa)                                                         \
    _Pragma("unroll")                                                          \
    for (int m = 0; m < 4; ++m) {                                              \
        float p[4][4];                                                         \
        _Pragma("unroll")                                                      \
        for (int f = 0; f < 4; ++f)                                            \
            _Pragma("unroll")                                                  \
            for (int r = 0; r < 4; ++r)                                        \
                p[f][r] = exp2_fast(st[m][f][r]);                              \
        uint4 u0, u1;                                                          \
        u0.x = pkbf(p[0][0], p[0][1]); u0.y = pkbf(p[0][2], p[0][3]);          \
        u0.z = pkbf(p[1][0], p[1][1]); u0.w = pkbf(p[1][2], p[1][3]);          \
        u1.x = pkbf(p[2][0], p[2][1]); u1.y = pkbf(p[2][2], p[2][3]);          \
        u1.z = pkbf(p[3][0], p[3][1]); u1.w = pkbf(p[3][2], p[3][3]);          \
        pa[m][0] = *(short8*)&u0;                                              \
        pa[m][1] = *(short8*)&u1;                                              \
    }

    #define PV(bb, pa)                                                         \
    _Pragma("unroll")                                                          \
    for (int s = 0; s < 2; ++s) {                                              \
        short8 vb[4];                                                          \
        _Pragma("unroll")                                                      \
        for (int df = 0; df < 4; ++df)                                         \
            vb[df] = *(const short8*)((char*)Vl[bb] + rdoff[s][df]);           \
        __builtin_amdgcn_s_setprio(1);                                         \
        _Pragma("unroll")                                                      \
        for (int m = 0; m < 4; ++m) {                                          \
            lacc[m] = __builtin_amdgcn_mfma_f32_16x16x32_bf16(                 \
                ones, pa[m][s], lacc[m], 0, 0, 0);                             \
            _Pragma("unroll")                                                  \
            for (int df = 0; df < 4; ++df)                                     \
                oacc[m][df] = __builtin_amdgcn_mfma_f32_16x16x32_bf16(         \
                    vb[df], pa[m][s], oacc[m][df], 0, 0, 0);                   \
        }                                                                      \
        __builtin_amdgcn_s_setprio(0);                                         \
    }

    #define BODY2(bA, bB, tt, PF)                                              \
    {                                                                          \
        asm volatile("s_waitcnt vmcnt(0)" ::: "memory");                       \
        __builtin_amdgcn_s_barrier();                                          \
        __builtin_amdgcn_sched_barrier(0);                                     \
        if (PF) { STAGE(bA ^ 2, (tt) + 2); STAGE(bB ^ 2, (tt) + 3); }          \
        f32x4 st[4][4];                                                        \
        short8 paA[4][2], paB[4][2];                                           \
        QK(bA, st)                                                             \
        SM(st, paA)                                                            \
        QK(bB, st)                                                             \
        PV(bA, paA)                                                            \
        SM(st, paB)                                                            \
        PV(bB, paB)                                                            \
    }

    for (int t = 0; t < NT; t += 4) {
        BODY2(0, 1, t,     true);
        BODY2(2, 3, t + 2, (t + 4 < NT));
    }
    #undef BODY2
    #undef QK
    #undef SM
    #undef PV
    #undef STAGE

    // ---- epilogue: l from lacc (col = lane's own q = c); half4 stores ----
    #pragma unroll
    for (int m = 0; m < 4; ++m) {
        const float iv = __builtin_amdgcn_rcpf(lacc[m][0]);
        const size_t t = (size_t)(b * SEQ + q0 + w * 64 + m * 16 + c);
        _Float16* orow = Of + t * 1024 + h * 64;
        #pragma unroll
        for (int df = 0; df < 4; ++df) {
            half4 o;
            o[0] = (_Float16)(oacc[m][df][0] * iv);
            o[1] = (_Float16)(oacc[m][df][1] * iv);
            o[2] = (_Float16)(oacc[m][df][2] * iv);
            o[3] = (_Float16)(oacc[m][df][3] * iv);
            *(half4*)(orow + df * 16 + 4 * g) = o;
        }
    }
}

// ---------------------------------------------------------------------------
extern "C" void kernel_launch(void* const* d_in, const int* in_sizes, int n_in,
                              void* d_out, int out_size, void* d_ws, size_t ws_size,
                              hipStream_t stream) {
    const float* x      = (const float*)d_in[0];
    const float* w_qkv  = (const float*)d_in[1];
    const float* w_proj = (const float*)d_in[2];
    const float* b_proj = (const float*)d_in[3];
    float* out = (float*)d_out;

    char* ws = (char*)d_ws;
    const size_t MB = 1024 * 1024;
    _Float16* Xf  = (_Float16*)(ws);             // 16 MB
    _Float16* Of  = Xf;                          // alias: X dead after qkv GEMM
    _Float16* Wf  = (_Float16*)(ws + 16 * MB);   // 6 MB
    _Float16* Wpf = (_Float16*)(ws + 22 * MB);   // 2 MB
    unsigned short* Qb = (unsigned short*)(ws + 24 * MB);  // 16 MB
    unsigned short* Kb = (unsigned short*)(ws + 40 * MB);  // 16 MB
    unsigned short* Vt = (unsigned short*)(ws + 56 * MB);  // 16 MB -> 72 MB total

    // 1) fp16 conversions (single launch)
    conv3<<<6144, 256, 0, stream>>>(x, Xf, w_qkv, Wf, w_proj, Wpf);

    // 2a) qkv GEMM, Q/K columns (B-direct, swapped epilogue)
    gemm_h<0, 1><<<512, 256, 0, stream>>>(
        Xf, Wf, 1024, 3072, 16, 0, nullptr, nullptr, Qb, Kb, Vt);
    // 2b) qkv GEMM, V columns (B-direct, unswapped epilogue)
    gemm_h<0, 0><<<256, 256, 0, stream>>>(
        Xf, Wf, 1024, 3072, 8, 2048, nullptr, nullptr, Qb, Kb, Vt);

    // 3) flash attention (2 tiles/barrier, 4-buffer, MFMA-l) -> Of
    attn_mfma<<<256, 512, 0, stream>>>(Qb, Kb, Vt, Of);

    // 4) proj GEMM (B-direct, float4 epilogue) + bias -> out
    gemm_h<1, 1><<<256, 256, 0, stream>>>(
        Of, Wpf, 1024, 1024, 8, 0, out, b_proj, nullptr, nullptr, nullptr);
}

// Round 26
// 173.005 us; speedup vs baseline: 1.1846x; 1.1846x over previous
//
#include <hip/hip_runtime.h>
#include <stdint.h>

#define NHEAD 16
#define SEQ 2048
#define BATCH 4
#define NT (SEQ / 64)   // 32 kv tiles of 64

typedef short short8 __attribute__((ext_vector_type(8)));     // 8 bf16 (4 VGPRs)
typedef _Float16 half8 __attribute__((ext_vector_type(8)));   // 8 fp16 (4 VGPRs)
typedef _Float16 half4 __attribute__((ext_vector_type(4)));   // 4 fp16 (8B)
typedef float f32x4  __attribute__((ext_vector_type(4)));     // MFMA accumulator
typedef __bf16 bf16x2 __attribute__((ext_vector_type(2)));

typedef const __attribute__((address_space(1))) void* gas_t;
typedef __attribute__((address_space(3))) void* las_t;
#define GLL16(g, s) __builtin_amdgcn_global_load_lds((gas_t)(g), (las_t)(s), 16, 0, 0)

static __device__ __forceinline__ unsigned short f2bfn(float f) {
    union { __bf16 b; unsigned short u; } cv;
    cv.b = (__bf16)f;
    return cv.u;
}
static __device__ __forceinline__ uint32_t pkbf(float a, float b) {
    union { bf16x2 v; uint32_t u; } cv;
    cv.v[0] = (__bf16)a; cv.v[1] = (__bf16)b;
    return cv.u;
}
static __device__ __forceinline__ float exp2_fast(float x) {
#if __has_builtin(__builtin_amdgcn_exp2f)
    return __builtin_amdgcn_exp2f(x);
#else
    float r; asm("v_exp_f32 %0, %1\n\ts_nop 0" : "=v"(r) : "v"(x)); return r;
#endif
}

// ---------------------------------------------------------------------------
// Merged fp32 -> fp16 conversion for x, w_qkv, w_proj (one launch).
// ---------------------------------------------------------------------------
__global__ __launch_bounds__(256)
void conv3(const float* __restrict__ x,  _Float16* __restrict__ Xf,
           const float* __restrict__ wq, _Float16* __restrict__ Wf,
           const float* __restrict__ wp, _Float16* __restrict__ Wpf) {
    const int bid = blockIdx.x;
    const float* src;
    _Float16* dst;
    int base;
    if (bid < 4096)      { src = x;  dst = Xf;  base = bid; }
    else if (bid < 5632) { src = wq; dst = Wf;  base = bid - 4096; }
    else                 { src = wp; dst = Wpf; base = bid - 5632; }
    const int idx = (base * 256 + threadIdx.x) * 8;
    float4 v0 = *(const float4*)(src + idx);
    float4 v1 = *(const float4*)(src + idx + 4);
    half8 h;
    h[0] = (_Float16)v0.x; h[1] = (_Float16)v0.y;
    h[2] = (_Float16)v0.z; h[3] = (_Float16)v0.w;
    h[4] = (_Float16)v1.x; h[5] = (_Float16)v1.y;
    h[6] = (_Float16)v1.z; h[7] = (_Float16)v1.w;
    *(half8*)(dst + idx) = h;
}

// ---------------------------------------------------------------------------
// fp16 MFMA GEMM (r24 exact, reverted from r25's B-direct regression):
// 256x128 macro-tile, 4 waves (2Mx2N), wave owns 128x64 (8x4 frags),
// 3-buffer depth-2 GLL16 (A+B in LDS), counted vmcnt(6), XCD grid,
// compile-time SWP operand order + vectorized epilogues.
// ---------------------------------------------------------------------------
template<int EPI, int SWP>
__global__ __launch_bounds__(256, 2)
void gemm_h(const _Float16* __restrict__ Af, const _Float16* __restrict__ Bf,
            int K, int N, int nbx, int bnoff,
            float* __restrict__ outF, const float* __restrict__ bias,
            unsigned short* __restrict__ Qb, unsigned short* __restrict__ Kb,
            unsigned short* __restrict__ Vt) {
    __shared__ _Float16 lds[3][12288];   // [buf][ A 256x32 | B 128x32 ]

    const int tid = threadIdx.x;
    const int l = tid & 63, wv = tid >> 6;
    const int wm = wv >> 1, wn = wv & 1;       // 2 M-waves x 2 N-waves
    const int c = l & 15, g = l >> 4;

    const int id = blockIdx.x;
    const int xcd = id & 7, s = id >> 3;
    const int bpx = (gridDim.x >> 3) / nbx;    // by-rows per XCD
    const int by = xcd * bpx + s / nbx, bx = s % nbx;
    const int bm = by * 256, bn = bnoff + bx * 128;

    size_t aoff[4], boff[2];
    int ldsA[4], ldsB[2];
    #pragma unroll
    for (int u = 0; u < 4; ++u) {
        const int i = u * 256 + tid;
        const int row = i >> 2;
        const int gg = (i & 3) ^ ((row >> 1) & 3);
        aoff[u] = (size_t)(bm + row) * K + gg * 8;
        ldsA[u] = (u * 256 + wv * 64) * 8;
    }
    #pragma unroll
    for (int u = 0; u < 2; ++u) {
        const int i = u * 256 + tid;
        const int row = i >> 2;
        const int gg = (i & 3) ^ ((row >> 1) & 3);
        boff[u] = (size_t)(bn + row) * K + gg * 8;
        ldsB[u] = 8192 + (u * 256 + wv * 64) * 8;
    }

    int offA[8], offB[4];
    #pragma unroll
    for (int m = 0; m < 8; ++m) {
        const int row = wm * 128 + m * 16 + c;
        offA[m] = row * 32 + (g ^ ((row >> 1) & 3)) * 8;
    }
    #pragma unroll
    for (int n = 0; n < 4; ++n) {
        const int row = wn * 64 + n * 16 + c;
        offB[n] = 8192 + row * 32 + (g ^ ((row >> 1) & 3)) * 8;
    }

    #define GSTAGE(buf, kk) do {                              \
        _Pragma("unroll")                                     \
        for (int u = 0; u < 4; ++u)                           \
            GLL16(Af + aoff[u] + (kk), &lds[buf][ldsA[u]]);   \
        _Pragma("unroll")                                     \
        for (int u = 0; u < 2; ++u)                           \
            GLL16(Bf + boff[u] + (kk), &lds[buf][ldsB[u]]);   \
    } while (0)

    f32x4 acc[8][4] = {};
    const int NK = K >> 5;

    GSTAGE(0, 0);
    GSTAGE(1, 32);
    asm volatile("s_waitcnt vmcnt(6)" ::: "memory");
    __builtin_amdgcn_s_barrier();
    __builtin_amdgcn_sched_barrier(0);

    for (int ks = 0; ks < NK; ++ks) {
        const int cur = ks % 3;
        if (ks + 2 < NK) GSTAGE((ks + 2) % 3, (ks + 2) * 32);

        half8 a[8], b[4];
        #pragma unroll
        for (int m = 0; m < 8; ++m) a[m] = *(const half8*)&lds[cur][offA[m]];
        #pragma unroll
        for (int n = 0; n < 4; ++n) b[n] = *(const half8*)&lds[cur][offB[n]];

        __builtin_amdgcn_s_setprio(1);
        #pragma unroll
        for (int m = 0; m < 8; ++m)
            #pragma unroll
            for (int n = 0; n < 4; ++n) {
                if constexpr (SWP)
                    acc[m][n] = __builtin_amdgcn_mfma_f32_16x16x32_f16(
                        b[n], a[m], acc[m][n], 0, 0, 0);
                else
                    acc[m][n] = __builtin_amdgcn_mfma_f32_16x16x32_f16(
                        a[m], b[n], acc[m][n], 0, 0, 0);
            }
        __builtin_amdgcn_s_setprio(0);

        if (ks + 1 < NK) {
            if (ks + 2 < NK) {
                asm volatile("s_waitcnt vmcnt(6)" ::: "memory");
            } else {
                asm volatile("s_waitcnt vmcnt(0)" ::: "memory");
            }
            __builtin_amdgcn_s_barrier();
            __builtin_amdgcn_sched_barrier(0);
        }
    }
    #undef GSTAGE

    if constexpr (EPI == 0) {
        const int colbase = bn + wn * 64;                   // 64-aligned
        const int which = colbase >> 10;
        const int h = (colbase >> 6) & 15;
        if constexpr (SWP) {
            const float qs = 0.125f * 1.44269504088896340736f;
            unsigned short* plane = (which == 0) ? Qb : Kb;
            const float sc = (which == 0) ? qs : 1.0f;
            #pragma unroll
            for (int m = 0; m < 8; ++m) {
                const int t = bm + wm * 128 + m * 16 + c;
                const int bb = t >> 11, nl = t & 2047;
                unsigned short* rowp = plane +
                    ((size_t)(bb * NHEAD + h) * SEQ + nl) * 64;
                #pragma unroll
                for (int n = 0; n < 4; ++n) {
                    ushort4 o;
                    o.x = f2bfn(acc[m][n][0] * sc);
                    o.y = f2bfn(acc[m][n][1] * sc);
                    o.z = f2bfn(acc[m][n][2] * sc);
                    o.w = f2bfn(acc[m][n][3] * sc);
                    *(ushort4*)(rowp + n * 16 + 4 * g) = o;
                }
            }
        } else {
            #pragma unroll
            for (int m = 0; m < 8; ++m) {
                const int trow0 = bm + wm * 128 + m * 16 + 4 * g;
                const int bb = trow0 >> 11, nl0 = trow0 & 2047;
                #pragma unroll
                for (int n = 0; n < 4; ++n) {
                    const int d = n * 16 + c;
                    ushort4 o;
                    o.x = f2bfn(acc[m][n][0]);
                    o.y = f2bfn(acc[m][n][1]);
                    o.z = f2bfn(acc[m][n][2]);
                    o.w = f2bfn(acc[m][n][3]);
                    *(ushort4*)(Vt + ((size_t)(bb * NHEAD + h) * 64 + d) * SEQ + nl0) = o;
                }
            }
        }
    } else {
        #pragma unroll
        for (int m = 0; m < 8; ++m) {
            const int t = bm + wm * 128 + m * 16 + c;
            #pragma unroll
            for (int n = 0; n < 4; ++n) {
                const int col0 = bn + wn * 64 + n * 16 + 4 * g;
                float4 bv = *(const float4*)&bias[col0];
                float4 o;
                o.x = acc[m][n][0] + bv.x;
                o.y = acc[m][n][1] + bv.y;
                o.z = acc[m][n][2] + bv.z;
                o.w = acc[m][n][3] + bv.w;
                *(float4*)&outF[(size_t)t * N + col0] = o;
            }
        }
    }
}

// ---------------------------------------------------------------------------
// MFMA flash attention (r24, unchanged): two tiles per barrier span, 4 LDS
// buffer pairs, shared-zero C, MFMA-l, tau' in-register P, swapped PV.
// ---------------------------------------------------------------------------
__global__ __launch_bounds__(512)
void attn_mfma(const unsigned short* __restrict__ Qb, const unsigned short* __restrict__ Kb,
               const unsigned short* __restrict__ Vt, _Float16* __restrict__ Of) {
    __shared__ unsigned short Kl[4][4096];   // [buf][64 row][64 d], rows = tau'-permuted kv
    __shared__ unsigned short Vl[4][4096];   // [buf][64 d][64 kv], natural kv

    const int tid = threadIdx.x;
    const int l = tid & 63, w = tid >> 6;
    const int g = l >> 4, c = l & 15;
    const int sw = (c & 7) << 4;

    const int blk = blockIdx.x;
    const int xcd = blk & 7, s0 = blk >> 3;        // s0 = 0..31
    const int bh = xcd * 8 + (s0 >> 2);
    const int b = bh >> 4, h = bh & 15;
    const int q0 = (s0 & 3) * 512;

    const unsigned short* QbBH = Qb + (size_t)bh * SEQ * 64;
    const unsigned short* KbBH = Kb + (size_t)bh * SEQ * 64;
    const unsigned short* VtBH = Vt + (size_t)bh * 64 * SEQ;

    const int r0 = tid >> 3;
    const int tau0 = (r0 & 32) | ((r0 & 12) << 1) | ((r0 & 16) >> 2) | (r0 & 3);
    const unsigned short* sK0 = KbBH + (size_t)tau0 * 64 + ((tid & 7) ^ (r0 & 7)) * 8;
    const unsigned short* sV0 = VtBH + (size_t)r0 * SEQ + ((tid & 7) ^ (r0 & 7)) * 8;

    #define STAGE(nb, tt) do {                                        \
        GLL16(sK0 + (size_t)(tt) * 4096, (char*)Kl[nb] + tid * 16);   \
        GLL16(sV0 + (tt) * 64,           (char*)Vl[nb] + tid * 16);   \
    } while (0)

    int rdoff[2][4];
    #pragma unroll
    for (int s = 0; s < 2; ++s)
        #pragma unroll
        for (int f = 0; f < 4; ++f)
            rdoff[s][f] = (f * 16 + c) * 128 + ((g * 16 + s * 64) ^ sw);

    short8 qf[4][2];
    #pragma unroll
    for (int m = 0; m < 4; ++m)
        #pragma unroll
        for (int s = 0; s < 2; ++s)
            qf[m][s] = *(const short8*)(QbBH +
                         (size_t)(q0 + w * 64 + m * 16 + c) * 64 + s * 32 + g * 8);

    const short8 ones = {0x3F80, 0x3F80, 0x3F80, 0x3F80,
                         0x3F80, 0x3F80, 0x3F80, 0x3F80};   // bf16 1.0
    const f32x4 z4 = {0.f, 0.f, 0.f, 0.f};                  // shared zero C-in

    f32x4 oacc[4][4] = {};
    f32x4 lacc[4] = {};

    STAGE(0, 0);
    STAGE(1, 1);

    #define QK(bb, st)                                                         \
    {                                                                          \
        short8 kf[4];                                                          \
        _Pragma("unroll")                                                      \
        for (int f = 0; f < 4; ++f)                                            \
            kf[f] = *(const short8*)((char*)Kl[bb] + rdoff[0][f]);             \
        __builtin_amdgcn_s_setprio(1);                                         \
        _Pragma("unroll")                                                      \
        for (int m = 0; m < 4; ++m)                                            \
            _Pragma("unroll")                                                  \
            for (int f = 0; f < 4; ++f)                                        \
                st[m][f] = __builtin_amdgcn_mfma_f32_16x16x32_bf16(            \
                    kf[f], qf[m][0], z4, 0, 0, 0);                             \
        __builtin_amdgcn_s_setprio(0);                                         \
        _Pragma("unroll")                                                      \
        for (int f = 0; f < 4; ++f)                                            \
            kf[f] = *(const short8*)((char*)Kl[bb] + rdoff[1][f]);             \
        __builtin_amdgcn_s_setprio(1);                                         \
        _Pragma("unroll")                                                      \
        for (int m = 0; m < 4; ++m)                                            \
            _Pragma("unroll")                                                  \
            for (int f = 0; f < 4; ++f)                                        \
                st[m][f] = __builtin_amdgcn_mfma_f32_16x16x32_bf16(            \
                    kf[f], qf[m][1], st[m][f], 0, 0, 0);                       \
        __builtin_amdgcn_s_setprio(0);                                         \
    }

    #define SM(st, pa)                                                         \
    _Pragma("unroll")                                                          \
    for (int m = 0; m < 4; ++m) {                                              \
        float p[4][4];                                                         \
        _Pragma("unroll")                                                      \
        for (int f = 0; f < 4; ++f)                                            \
            _Pragma("unroll")                                                  \
            for (int r = 0; r < 4; ++r)                                        \
                p[f][r] = exp2_fast(st[m][f][r]);                              \
        uint4 u0, u1;                                                          \
        u0.x = pkbf(p[0][0], p[0][1]); u0.y = pkbf(p[0][2], p[0][3]);          \
        u0.z = pkbf(p[1][0], p[1][1]); u0.w = pkbf(p[1][2], p[1][3]);          \
        u1.x = pkbf(p[2][0], p[2][1]); u1.y = pkbf(p[2][2], p[2][3]);          \
        u1.z = pkbf(p[3][0], p[3][1]); u1.w = pkbf(p[3][2], p[3][3]);          \
        pa[m][0] = *(short8*)&u0;                                              \
        pa[m][1] = *(short8*)&u1;                                              \
    }

    #define PV(bb, pa)                                                         \
    _Pragma("unroll")                                                          \
    for (int s = 0; s < 2; ++s) {                                              \
        short8 vb[4];                                                          \
        _Pragma("unroll")                                                      \
        for (int df = 0; df < 4; ++df)                                         \
            vb[df] = *(const short8*)((char*)Vl[bb] + rdoff[s][df]);           \
        __builtin_amdgcn_s_setprio(1);                                         \
        _Pragma("unroll")                                                      \
        for (int m = 0; m < 4; ++m) {                                          \
            lacc[m] = __builtin_amdgcn_mfma_f32_16x16x32_bf16(                 \
                ones, pa[m][s], lacc[m], 0, 0, 0);                             \
            _Pragma("unroll")                                                  \
            for (int df = 0; df < 4; ++df)                                     \
                oacc[m][df] = __builtin_amdgcn_mfma_f32_16x16x32_bf16(         \
                    vb[df], pa[m][s], oacc[m][df], 0, 0, 0);                   \
        }                                                                      \
        __builtin_amdgcn_s_setprio(0);                                         \
    }

    #define BODY2(bA, bB, tt, PF)                                              \
    {                                                                          \
        asm volatile("s_waitcnt vmcnt(0)" ::: "memory");                       \
        __builtin_amdgcn_s_barrier();                                          \
        __builtin_amdgcn_sched_barrier(0);                                     \
        if (PF) { STAGE(bA ^ 2, (tt) + 2); STAGE(bB ^ 2, (tt) + 3); }          \
        f32x4 st[4][4];                                                        \
        short8 paA[4][2], paB[4][2];                                           \
        QK(bA, st)                                                             \
        SM(st, paA)                                                            \
        QK(bB, st)                                                             \
        PV(bA, paA)                                                            \
        SM(st, paB)                                                            \
        PV(bB, paB)                                                            \
    }

    for (int t = 0; t < NT; t += 4) {
        BODY2(0, 1, t,     true);
        BODY2(2, 3, t + 2, (t + 4 < NT));
    }
    #undef BODY2
    #undef QK
    #undef SM
    #undef PV
    #undef STAGE

    // ---- epilogue: l from lacc (col = lane's own q = c); half4 stores ----
    #pragma unroll
    for (int m = 0; m < 4; ++m) {
        const float iv = __builtin_amdgcn_rcpf(lacc[m][0]);
        const size_t t = (size_t)(b * SEQ + q0 + w * 64 + m * 16 + c);
        _Float16* orow = Of + t * 1024 + h * 64;
        #pragma unroll
        for (int df = 0; df < 4; ++df) {
            half4 o;
            o[0] = (_Float16)(oacc[m][df][0] * iv);
            o[1] = (_Float16)(oacc[m][df][1] * iv);
            o[2] = (_Float16)(oacc[m][df][2] * iv);
            o[3] = (_Float16)(oacc[m][df][3] * iv);
            *(half4*)(orow + df * 16 + 4 * g) = o;
        }
    }
}

// ---------------------------------------------------------------------------
extern "C" void kernel_launch(void* const* d_in, const int* in_sizes, int n_in,
                              void* d_out, int out_size, void* d_ws, size_t ws_size,
                              hipStream_t stream) {
    const float* x      = (const float*)d_in[0];
    const float* w_qkv  = (const float*)d_in[1];
    const float* w_proj = (const float*)d_in[2];
    const float* b_proj = (const float*)d_in[3];
    float* out = (float*)d_out;

    char* ws = (char*)d_ws;
    const size_t MB = 1024 * 1024;
    _Float16* Xf  = (_Float16*)(ws);             // 16 MB
    _Float16* Of  = Xf;                          // alias: X dead after qkv GEMM
    _Float16* Wf  = (_Float16*)(ws + 16 * MB);   // 6 MB
    _Float16* Wpf = (_Float16*)(ws + 22 * MB);   // 2 MB
    unsigned short* Qb = (unsigned short*)(ws + 24 * MB);  // 16 MB
    unsigned short* Kb = (unsigned short*)(ws + 40 * MB);  // 16 MB
    unsigned short* Vt = (unsigned short*)(ws + 56 * MB);  // 16 MB -> 72 MB total

    // 1) fp16 conversions (single launch)
    conv3<<<6144, 256, 0, stream>>>(x, Xf, w_qkv, Wf, w_proj, Wpf);

    // 2a) qkv GEMM, Q/K columns (256x128 wide-wave, swapped epilogue)
    gemm_h<0, 1><<<512, 256, 0, stream>>>(
        Xf, Wf, 1024, 3072, 16, 0, nullptr, nullptr, Qb, Kb, Vt);
    // 2b) qkv GEMM, V columns (256x128 wide-wave, unswapped epilogue)
    gemm_h<0, 0><<<256, 256, 0, stream>>>(
        Xf, Wf, 1024, 3072, 8, 2048, nullptr, nullptr, Qb, Kb, Vt);

    // 3) flash attention (2 tiles/barrier, 4-buffer, MFMA-l) -> Of
    attn_mfma<<<256, 512, 0, stream>>>(Qb, Kb, Vt, Of);

    // 4) proj GEMM (256x128 wide-wave, float4 epilogue) + bias -> out
    gemm_h<1, 1><<<256, 256, 0, stream>>>(
        Of, Wpf, 1024, 1024, 8, 0, out, b_proj, nullptr, nullptr, nullptr);
}